// Round 14
// baseline (150.486 us; speedup 1.0000x reference)
//
#include <hip/hip_runtime.h>
#include <stdint.h>

// Geometry (fixed): B=4, C=512, H=W=64
#define NB 4
#define CB 512
#define HH 64
#define WW 64
#define HW 4096
#define C4 2048
#define PTOT (NB*HW)   // 16384 pixels across batch

typedef float  f32x4  __attribute__((ext_vector_type(4)));
typedef short  bf16x8 __attribute__((ext_vector_type(8)));

__device__ __forceinline__ float relu_f(float v){ return v > 0.f ? v : 0.f; }

__device__ __forceinline__ float bf2f(unsigned short u){
    union { uint32_t i; float f; } v; v.i = ((uint32_t)u) << 16; return v.f;
}
__device__ __forceinline__ unsigned short f2bf(float f){
    union { float f; uint32_t i; } v; v.f = f;
    uint32_t r = v.i + 0x7FFFu + ((v.i >> 16) & 1u);   // RNE
    return (unsigned short)(r >> 16);
}

__device__ __forceinline__ void gload16(const void* g, void* l){
    __builtin_amdgcn_global_load_lds(
        (const __attribute__((address_space(1))) uint32_t*)g,
        (__attribute__((address_space(3))) uint32_t*)l, 16, 0, 0);
}

// ---------------------------------------------------------------------------
// Fused prep: blocks [0,2048) transpose+cast x -> xT ; blocks [2048,4352)
// cast the three weight matrices fp32 -> bf16 (one launch instead of two).
// ---------------------------------------------------------------------------
__global__ __launch_bounds__(256) void prep_fused(
    const float* __restrict__ x, unsigned short* __restrict__ xT,
    const float* __restrict__ a, unsigned short* __restrict__ oa,
    const float* __restrict__ b, unsigned short* __restrict__ ob,
    const float* __restrict__ c, unsigned short* __restrict__ oc)
{
    const int t = threadIdx.x;
    if (blockIdx.x >= 2048) {
        int i = (blockIdx.x - 2048) * 256 + t;
        const float* src; unsigned short* dst; int j;
        if (i < 65536)        { src = a; dst = oa; j = i; }
        else if (i < 327680)  { src = b; dst = ob; j = i - 65536; }
        else                  { src = c; dst = oc; j = i - 327680; }
        float4 v = ((const float4*)src)[j];
        ushort4 o;
        o.x = f2bf(v.x); o.y = f2bf(v.y); o.z = f2bf(v.z); o.w = f2bf(v.w);
        ((ushort4*)dst)[j] = o;
        return;
    }
    __shared__ unsigned short tile[64][72];
    const int tb = blockIdx.x;            // 0..2047
    const int p0 = (tb & 63) * 64;
    const int c0 = ((tb >> 6) & 7) * 64;
    const int bb = tb >> 9;

    const int pl = (t & 15) * 4;
    const int cl = t >> 4;
    const float* src = x + ((size_t)bb * CB + c0) * HW + p0;
    #pragma unroll
    for (int r = 0; r < 4; r++) {
        int c2 = cl + r * 16;
        float4 v = *(const float4*)(src + (size_t)c2 * HW + pl);
        tile[pl + 0][c2] = f2bf(v.x);
        tile[pl + 1][c2] = f2bf(v.y);
        tile[pl + 2][c2] = f2bf(v.z);
        tile[pl + 3][c2] = f2bf(v.w);
    }
    __syncthreads();
    unsigned short* dst = xT + ((size_t)bb * HW + p0) * CB + c0;
    const int cl2 = (t & 15) * 4;
    const int pl2 = t >> 4;
    #pragma unroll
    for (int r = 0; r < 4; r++) {
        int p = pl2 + r * 16;
        ushort4 o = *(ushort4*)&tile[p][cl2];
        *(ushort4*)(dst + (size_t)p * CB + cl2) = o;
    }
}

// ---------------------------------------------------------------------------
// Channel-last MFMA GEMM, 128p x 256o block tile (LDS-traffic cut):
//   D[p][o] = sum_k A[p][k] * Bw[o][k]  (bf16 in, f32 acc)
// 4 waves (2m x 2n), wave-tile 64x128 (acc 4x8 f32x4 = 128 VGPR), BK=64.
// Rationale (R13 counters): 128^2 tile = 64KB LDS frag-reads per tile vs
// 621cy MFMA -> LDS-pipe bound (1612cy/tile measured ~= LDS+MFMA serial).
// 128x256 tile reads 96KB for 2x FLOP = -25% bytes/FLOP; MFMA 1242cy ~=
// LDS 1130cy per CU per tile -> balanced. LDS 2x48K dbuf = 96K -> 1 blk/CU,
// grid (128,2)=256 blocks; per-tile compute ~1242cy > 900cy HBM latency so
// depth-1 prefetch still covers. Same proven 2-barrier counted-vmcnt loop:
// STAGE(t+1) [12 loads] ; vmcnt(12) ; barrier ; COMPUTE ; barrier.
// o-pair of a p-panel is 128 apart in lin, 128%8==0 -> same XCD (L2 reuse).
// OUTMODE 0: bf16 [PTOT][512] channel-last; 1: fp32 [b][512][HW] + ReLU.
// ---------------------------------------------------------------------------
template<int K, int OUTMODE>
__global__ __launch_bounds__(256) void gemm_cl(
    const unsigned short* __restrict__ A,
    const unsigned short* __restrict__ Bw,
    void* __restrict__ out)
{
    __shared__ __align__(16) char lds[98304];   // 2 x (A 16K | B 32K)

    const int t    = threadIdx.x;
    const int lane = t & 63;
    const int wid  = t >> 6;
    const int p0   = blockIdx.x * 128;
    const int o0   = blockIdx.y * 256;

    const int l15 = lane & 15;
    const int l4  = lane >> 4;
    const int wm  = (wid >> 1) * 64;   // wave p-offset (0,64)
    const int wn  = (wid & 1) * 128;   // wave o-offset (0,128)
    const int rowA = wm + l15;
    const int swz  = (l15 & 7) << 4;   // row&7 == l15&7 for both operands

    f32x4 acc[4][8];
    #pragma unroll
    for (int m = 0; m < 4; m++)
        #pragma unroll
        for (int n = 0; n < 8; n++) acc[m][n] = (f32x4)0.f;

    const int srow  = t >> 3;          // 0..31 (+q*32)
    const int scolb = (t & 7) * 16;

    auto STAGE = [&](int k0, int off) {
        #pragma unroll
        for (int q = 0; q < 4; q++) {          // A: 128 rows
            const int row = q * 32 + srow;
            const int kk  = k0 + ((scolb ^ ((row & 7) << 4)) >> 1);
            gload16(A + (size_t)(p0 + row) * K + kk,
                    lds + off + q * 4096 + wid * 1024);
        }
        #pragma unroll
        for (int q = 0; q < 8; q++) {          // B: 256 rows
            const int row = q * 32 + srow;
            const int kk  = k0 + ((scolb ^ ((row & 7) << 4)) >> 1);
            gload16(Bw + (size_t)(o0 + row) * K + kk,
                    lds + off + 16384 + q * 4096 + wid * 1024);
        }
    };
    auto COMPUTE = [&](int off) {
        const char* cA = lds + off;
        const char* cB = lds + off + 16384;
        #pragma unroll
        for (int kh = 0; kh < 2; kh++) {
            const int colb = kh * 64 + l4 * 16;
            bf16x8 a[4], b[8];
            #pragma unroll
            for (int m = 0; m < 4; m++)
                a[m] = *(const bf16x8*)(cA + (rowA + m * 16) * 128 + (colb ^ swz));
            #pragma unroll
            for (int n = 0; n < 8; n++)
                b[n] = *(const bf16x8*)(cB + (wn + n * 16 + l15) * 128 + (colb ^ swz));
            #pragma unroll
            for (int m = 0; m < 4; m++)
                #pragma unroll
                for (int n = 0; n < 8; n++)
                    acc[m][n] = __builtin_amdgcn_mfma_f32_16x16x32_bf16(
                                    a[m], b[n], acc[m][n], 0, 0, 0);
        }
    };

    const int NT = K / 64;
    STAGE(0, 0);                                    // 12 loads in flight
    #pragma unroll 1
    for (int tt = 0; tt < NT; ++tt) {
        const int cur = (tt & 1) * 49152;
        const int nxt = 49152 - cur;
        if (tt + 1 < NT) {
            STAGE((tt + 1) * 64, nxt);              // +12 loads (tile t+1)
            asm volatile("s_waitcnt vmcnt(12)" ::: "memory");  // drain tile t's 12
        } else {
            asm volatile("s_waitcnt vmcnt(0)" ::: "memory");
        }
        __builtin_amdgcn_s_barrier();               // tile t resident everywhere
        __builtin_amdgcn_sched_barrier(0);
        COMPUTE(cur);                               // prefetch stays in flight
        __builtin_amdgcn_s_barrier();               // all reads of cur done
    }

    if (OUTMODE == 0) {
        unsigned short* op = (unsigned short*)out;
        #pragma unroll
        for (int m = 0; m < 4; m++)
            #pragma unroll
            for (int r = 0; r < 4; r++) {
                const int p = p0 + wm + m * 16 + l4 * 4 + r;
                #pragma unroll
                for (int n = 0; n < 8; n++) {
                    const int o = o0 + wn + n * 16 + l15;
                    op[(size_t)p * CB + o] = f2bf(acc[m][n][r]);
                }
            }
    } else {
        // fp32 channel-first + ReLU via LDS transpose, four o-halves of 64
        __syncthreads();                   // protect LDS reuse vs last COMPUTE
        float (*tl)[132] = (float(*)[132])lds;   // 64*132*4 = 33792 < 98304
        const int bb   = p0 >> 12;
        const int phw0 = p0 & (HW - 1);
        #pragma unroll
        for (int h = 0; h < 4; h++) {
            if ((wid & 1) == (h >> 1)) {
                #pragma unroll
                for (int n4 = 0; n4 < 4; n4++) {
                    const int n = (h & 1) * 4 + n4;
                    #pragma unroll
                    for (int m = 0; m < 4; m++)
                        #pragma unroll
                        for (int r = 0; r < 4; r++)
                            tl[n4 * 16 + l15][wm + m * 16 + l4 * 4 + r] = acc[m][n][r];
                }
            }
            __syncthreads();
            const int orow = t >> 2;            // 0..63
            const int pseg = (t & 3) * 32;      // 0..96
            float* dst = (float*)out +
                ((size_t)(bb * CB + o0 + h * 64 + orow)) * HW + phw0 + pseg;
            #pragma unroll
            for (int j = 0; j < 8; j++) {
                float4 v = *(float4*)&tl[orow][pseg + j * 4];
                v.x = relu_f(v.x); v.y = relu_f(v.y); v.z = relu_f(v.z); v.w = relu_f(v.w);
                *(float4*)(dst + j * 4) = v;
            }
            __syncthreads();
        }
    }
}

// ---------------------------------------------------------------------------
// Fused 4-direction IRNN scan, channel-last, scalar channel per thread.
// grid (512, 4): blockIdx.y = dir (0=u,1=r,2=d,3=l). Depth-8 reg prefetch.
// ---------------------------------------------------------------------------
__global__ __launch_bounds__(256) void irnn_fused(
    const unsigned short* __restrict__ in, unsigned short* __restrict__ outc,
    const float* __restrict__ wu, const float* __restrict__ bu,
    const float* __restrict__ wr, const float* __restrict__ br,
    const float* __restrict__ wd, const float* __restrict__ bd,
    const float* __restrict__ wl, const float* __restrict__ bl)
{
    const int dir = blockIdx.y;
    const float* wv; const float* bv; int pstep, rev;
    if      (dir == 0) { wv = wu; bv = bu; pstep = 64; rev = 1; }  // up
    else if (dir == 1) { wv = wr; bv = br; pstep = 1;  rev = 0; }  // right
    else if (dir == 2) { wv = wd; bv = bd; pstep = 64; rev = 0; }  // down
    else               { wv = wl; bv = bl; pstep = 1;  rev = 1; }  // left
    const int dirOff = dir * 512;

    const int idx = blockIdx.x * 256 + threadIdx.x;  // 0..131071
    const int c = idx & 511;
    const int f = (idx >> 9) & 63;
    const int b = idx >> 15;
    const int fbase = (pstep == 64) ? f : f * 64;

    const float wc = wv[c], bc = bv[c];
    const int t0 = rev ? 63 : 0;
    const int dp = rev ? -pstep : pstep;
    const int istep = dp * CB;
    const int ostep = dp * C4;

    const unsigned short* ip = in   + ((size_t)b * HW + fbase + (size_t)t0 * pstep) * CB + c;
    unsigned short*       op = outc + ((size_t)b * HW + fbase + (size_t)t0 * pstep) * C4 + dirOff + c;

    float s = relu_f(bf2f(ip[0]));
    op[0] = 0;

    unsigned short v0 = ip[1*istep], v1 = ip[2*istep], v2 = ip[3*istep], v3 = ip[4*istep],
                   v4 = ip[5*istep], v5 = ip[6*istep], v6 = ip[7*istep], v7 = ip[8*istep];

#define DO(kk, vv) { s = relu_f(fmaf(s, wc, bc + bf2f(vv))); op[(kk)*ostep] = f2bf(s); }
    for (int g = 0; g < 6; ++g) {
        const int k0 = 1 + 8 * g;
        DO(k0+0, v0); v0 = ip[(k0+ 8)*istep];
        DO(k0+1, v1); v1 = ip[(k0+ 9)*istep];
        DO(k0+2, v2); v2 = ip[(k0+10)*istep];
        DO(k0+3, v3); v3 = ip[(k0+11)*istep];
        DO(k0+4, v4); v4 = ip[(k0+12)*istep];
        DO(k0+5, v5); v5 = ip[(k0+13)*istep];
        DO(k0+6, v6); v6 = ip[(k0+14)*istep];
        DO(k0+7, v7); v7 = ip[(k0+15)*istep];
    }
    DO(49, v0); v0 = ip[57*istep];
    DO(50, v1); v1 = ip[58*istep];
    DO(51, v2); v2 = ip[59*istep];
    DO(52, v3); v3 = ip[60*istep];
    DO(53, v4); v4 = ip[61*istep];
    DO(54, v5); v5 = ip[62*istep];
    DO(55, v6); v6 = ip[63*istep];
    DO(56, v7);
    DO(57, v0); DO(58, v1); DO(59, v2); DO(60, v3);
    DO(61, v4); DO(62, v5); DO(63, v6);
#undef DO
}

// ---------------------------------------------------------------------------
// ws map: [0,16M) xT | [16M,80M) concat_T | [80M,96M) out0/mid |
//         [96M,..) bf16 weights. conv3x3 "attention" branch is dead -> skipped.
// 6 dispatches: prep | gemm512 | scan1 | gemm2048 | scan2 | gemm2048+relu.
// ---------------------------------------------------------------------------
extern "C" void kernel_launch(void* const* d_in, const int* in_sizes, int n_in,
                              void* d_out, int out_size, void* d_ws, size_t ws_size,
                              hipStream_t stream) {
    const float* x     = (const float*)d_in[0];
    const float* cin_w = (const float*)d_in[7];
    const float* c2_w  = (const float*)d_in[8];
    const float* c3_w  = (const float*)d_in[9];
    const float* i1_wu = (const float*)d_in[10];
    const float* i1_bu = (const float*)d_in[11];
    const float* i1_wr = (const float*)d_in[12];
    const float* i1_br = (const float*)d_in[13];
    const float* i1_wd = (const float*)d_in[14];
    const float* i1_bd = (const float*)d_in[15];
    const float* i1_wl = (const float*)d_in[16];
    const float* i1_bl = (const float*)d_in[17];
    const float* i2_wu = (const float*)d_in[18];
    const float* i2_bu = (const float*)d_in[19];
    const float* i2_wr = (const float*)d_in[20];
    const float* i2_br = (const float*)d_in[21];
    const float* i2_wd = (const float*)d_in[22];
    const float* i2_bd = (const float*)d_in[23];
    const float* i2_wl = (const float*)d_in[24];
    const float* i2_bl = (const float*)d_in[25];

    char* ws = (char*)d_ws;
    unsigned short* xT     = (unsigned short*)(ws);
    unsigned short* concat = (unsigned short*)(ws + (size_t)16 * 1024 * 1024);
    unsigned short* mid    = (unsigned short*)(ws + (size_t)80 * 1024 * 1024);
    unsigned short* wA     = (unsigned short*)(ws + (size_t)96 * 1024 * 1024);
    unsigned short* wB     = (unsigned short*)(wA + 512 * 512);
    unsigned short* wC     = (unsigned short*)(wB + 512 * 2048);

    // 1) prep: x transpose+cast AND weight casts in one launch
    prep_fused<<<4352, 256, 0, stream>>>(x, xT, cin_w, wA, c2_w, wB, c3_w, wC);

    dim3 ggrid(PTOT/128, CB/256);    // 128 x 2 = 256 blocks = 1/CU
    dim3 sgrid(512, 4);

    // 2) out0_T = xT @ cin_w^T
    gemm_cl<512, 0><<<ggrid, 256, 0, stream>>>(xT, wA, mid);

    // 3) IRNN #1 -> concat_T
    irnn_fused<<<sgrid, 256, 0, stream>>>(mid, concat,
        i1_wu, i1_bu, i1_wr, i1_br, i1_wd, i1_bd, i1_wl, i1_bl);

    // 4) mid_T = concat_T @ c2_w^T
    gemm_cl<2048, 0><<<ggrid, 256, 0, stream>>>(concat, wB, mid);

    // 5) IRNN #2 -> concat_T
    irnn_fused<<<sgrid, 256, 0, stream>>>(mid, concat,
        i2_wu, i2_bu, i2_wr, i2_br, i2_wd, i2_bd, i2_wl, i2_bl);

    // 6) d_out = relu(concat_T @ c3_w^T), fp32 channel-first
    gemm_cl<2048, 1><<<ggrid, 256, 0, stream>>>(concat, wC, d_out);
}

// Round 15
// 140.849 us; speedup vs baseline: 1.0684x; 1.0684x over previous
//
#include <hip/hip_runtime.h>
#include <stdint.h>

// Geometry (fixed): B=4, C=512, H=W=64
#define NB 4
#define CB 512
#define HH 64
#define WW 64
#define HW 4096
#define C4 2048
#define PTOT (NB*HW)   // 16384 pixels across batch

typedef float  f32x4  __attribute__((ext_vector_type(4)));
typedef short  bf16x8 __attribute__((ext_vector_type(8)));

__device__ __forceinline__ float relu_f(float v){ return v > 0.f ? v : 0.f; }

__device__ __forceinline__ float bf2f(unsigned short u){
    union { uint32_t i; float f; } v; v.i = ((uint32_t)u) << 16; return v.f;
}
__device__ __forceinline__ unsigned short f2bf(float f){
    union { float f; uint32_t i; } v; v.f = f;
    uint32_t r = v.i + 0x7FFFu + ((v.i >> 16) & 1u);   // RNE
    return (unsigned short)(r >> 16);
}

__device__ __forceinline__ void gload16(const void* g, void* l){
    __builtin_amdgcn_global_load_lds(
        (const __attribute__((address_space(1))) uint32_t*)g,
        (__attribute__((address_space(3))) uint32_t*)l, 16, 0, 0);
}

// ---------------------------------------------------------------------------
// Fused prep: blocks [0,2048) transpose+cast x -> xT ; blocks [2048,4352)
// cast the three weight matrices fp32 -> bf16 (one launch instead of two).
// ---------------------------------------------------------------------------
__global__ __launch_bounds__(256) void prep_fused(
    const float* __restrict__ x, unsigned short* __restrict__ xT,
    const float* __restrict__ a, unsigned short* __restrict__ oa,
    const float* __restrict__ b, unsigned short* __restrict__ ob,
    const float* __restrict__ c, unsigned short* __restrict__ oc)
{
    const int t = threadIdx.x;
    if (blockIdx.x >= 2048) {
        int i = (blockIdx.x - 2048) * 256 + t;
        const float* src; unsigned short* dst; int j;
        if (i < 65536)        { src = a; dst = oa; j = i; }
        else if (i < 327680)  { src = b; dst = ob; j = i - 65536; }
        else                  { src = c; dst = oc; j = i - 327680; }
        float4 v = ((const float4*)src)[j];
        ushort4 o;
        o.x = f2bf(v.x); o.y = f2bf(v.y); o.z = f2bf(v.z); o.w = f2bf(v.w);
        ((ushort4*)dst)[j] = o;
        return;
    }
    __shared__ unsigned short tile[64][72];
    const int tb = blockIdx.x;            // 0..2047
    const int p0 = (tb & 63) * 64;
    const int c0 = ((tb >> 6) & 7) * 64;
    const int bb = tb >> 9;

    const int pl = (t & 15) * 4;
    const int cl = t >> 4;
    const float* src = x + ((size_t)bb * CB + c0) * HW + p0;
    #pragma unroll
    for (int r = 0; r < 4; r++) {
        int c2 = cl + r * 16;
        float4 v = *(const float4*)(src + (size_t)c2 * HW + pl);
        tile[pl + 0][c2] = f2bf(v.x);
        tile[pl + 1][c2] = f2bf(v.y);
        tile[pl + 2][c2] = f2bf(v.z);
        tile[pl + 3][c2] = f2bf(v.w);
    }
    __syncthreads();
    unsigned short* dst = xT + ((size_t)bb * HW + p0) * CB + c0;
    const int cl2 = (t & 15) * 4;
    const int pl2 = t >> 4;
    #pragma unroll
    for (int r = 0; r < 4; r++) {
        int p = pl2 + r * 16;
        ushort4 o = *(ushort4*)&tile[p][cl2];
        *(ushort4*)(dst + (size_t)p * CB + cl2) = o;
    }
}

// ---------------------------------------------------------------------------
// Channel-last MFMA GEMM (R13 winner, session best — kept verbatim):
//   D[p][o] = sum_k A[p][k] * Bw[o][k]  (bf16, f32 acc)
// Tile 128p x 128o, BK=64, 4 waves, 4x4 16x16x32 frags/wave.
// LDS: 2 x (A 16K | B 16K) = 64K static -> 2 blocks/CU (cross-block overlap
// is the latency hiding; all phase-split/bigger-tile variants R5-R14 lost).
// Loop: STAGE(t+1) ; vmcnt(8) ; barrier ; COMPUTE (hoisted 16 ds_reads,
// no setprio) ; barrier.
// OUTMODE 0: bf16 [PTOT][512] channel-last; 1: fp32 [b][512][HW] + ReLU.
// ---------------------------------------------------------------------------
template<int K, int OUTMODE>
__global__ __launch_bounds__(256) void gemm_cl(
    const unsigned short* __restrict__ A,
    const unsigned short* __restrict__ Bw,
    void* __restrict__ out)
{
    __shared__ __align__(16) char lds[65536];

    const int t    = threadIdx.x;
    const int lane = t & 63;
    const int wid  = t >> 6;
    const int p0   = blockIdx.x * 128;
    const int o0   = blockIdx.y * 128;

    const int l15 = lane & 15;
    const int l4  = lane >> 4;
    const int wp  = (wid & 1) * 64;
    const int wo  = (wid >> 1) * 64;
    const int rowA = wp + l15;
    const int rowB = wo + l15;
    const int swzA = (rowA & 7) << 4;
    const int swzB = (rowB & 7) << 4;

    f32x4 acc[4][4];
    #pragma unroll
    for (int m = 0; m < 4; m++)
        #pragma unroll
        for (int n = 0; n < 4; n++) acc[m][n] = (f32x4)0.f;

    const int srow  = t >> 3;
    const int scolb = (t & 7) * 16;

    auto STAGE = [&](int k0, char* base) {
        #pragma unroll
        for (int q = 0; q < 4; q++) {
            const int row = q * 32 + srow;
            const int kk  = k0 + ((scolb ^ ((row & 7) << 4)) >> 1);
            gload16(A  + (size_t)(p0 + row) * K + kk, base +         q * 4096 + wid * 1024);
            gload16(Bw + (size_t)(o0 + row) * K + kk, base + 16384 + q * 4096 + wid * 1024);
        }
    };
    auto COMPUTE = [&](const char* base) {
        const char* cA = base;
        const char* cB = base + 16384;
        bf16x8 a2[2][4], b2[2][4];
        #pragma unroll
        for (int kh = 0; kh < 2; kh++) {
            const int colb = kh * 64 + l4 * 16;
            #pragma unroll
            for (int m = 0; m < 4; m++)
                a2[kh][m] = *(const bf16x8*)(cA + (rowA + m * 16) * 128 + (colb ^ swzA));
            #pragma unroll
            for (int n = 0; n < 4; n++)
                b2[kh][n] = *(const bf16x8*)(cB + (rowB + n * 16) * 128 + (colb ^ swzB));
        }
        #pragma unroll
        for (int kh = 0; kh < 2; kh++)
            #pragma unroll
            for (int m = 0; m < 4; m++)
                #pragma unroll
                for (int n = 0; n < 4; n++)
                    acc[m][n] = __builtin_amdgcn_mfma_f32_16x16x32_bf16(
                                    a2[kh][m], b2[kh][n], acc[m][n], 0, 0, 0);
    };

    const int NT = K / 64;
    STAGE(0, lds);                                  // 8 loads in flight
    #pragma unroll 2
    for (int tt = 0; tt < NT - 1; ++tt) {
        char* cbase = lds + ((tt & 1) ? 32768 : 0);
        char* nbase = lds + ((tt & 1) ? 0 : 32768);
        STAGE((tt + 1) * 64, nbase);                // +8 loads (tile t+1)
        asm volatile("s_waitcnt vmcnt(8)" ::: "memory");  // drain ONLY tile t's 8
        __builtin_amdgcn_s_barrier();               // tile t resident everywhere
        __builtin_amdgcn_sched_barrier(0);
        COMPUTE(cbase);                             // MFMA current (prefetch in flight)
        __builtin_amdgcn_s_barrier();               // all reads of cbase done
    }
    asm volatile("s_waitcnt vmcnt(0)" ::: "memory");
    __builtin_amdgcn_s_barrier();
    __builtin_amdgcn_sched_barrier(0);
    COMPUTE(lds + (((NT - 1) & 1) ? 32768 : 0));

    if (OUTMODE == 0) {
        unsigned short* op = (unsigned short*)out;
        #pragma unroll
        for (int m = 0; m < 4; m++)
            #pragma unroll
            for (int r = 0; r < 4; r++) {
                const int p = p0 + wp + m * 16 + l4 * 4 + r;
                #pragma unroll
                for (int n = 0; n < 4; n++) {
                    const int o = wo + n * 16 + l15 + o0;
                    op[(size_t)p * CB + o] = f2bf(acc[m][n][r]);
                }
            }
    } else {
        __syncthreads();                   // protect LDS reuse vs last COMPUTE reads
        float (*tl)[132] = (float(*)[132])lds;
        const int bb   = p0 >> 12;
        const int phw0 = p0 & (HW - 1);
        #pragma unroll
        for (int half = 0; half < 2; half++) {
            if ((wid >> 1) == half) {
                #pragma unroll
                for (int n = 0; n < 4; n++)
                    #pragma unroll
                    for (int m = 0; m < 4; m++)
                        #pragma unroll
                        for (int r = 0; r < 4; r++)
                            tl[n * 16 + l15][wp + m * 16 + l4 * 4 + r] = acc[m][n][r];
            }
            __syncthreads();
            const int orow = t >> 2;
            const int pseg = (t & 3) * 32;
            float* dst = (float*)out +
                ((size_t)(bb * CB + o0 + half * 64 + orow)) * HW + phw0 + pseg;
            #pragma unroll
            for (int j = 0; j < 8; j++) {
                float4 v = *(float4*)&tl[orow][pseg + j * 4];
                v.x = relu_f(v.x); v.y = relu_f(v.y); v.z = relu_f(v.z); v.w = relu_f(v.w);
                *(float4*)(dst + j * 4) = v;
            }
            __syncthreads();
        }
    }
}

// ---------------------------------------------------------------------------
// Fused 4-direction IRNN scan, channel-last, CHANNEL-PAIR per thread
// (ushort2: 4B/lane stores -> 256B/wave, half the store instructions of the
// scalar version). grid (256, 4): blockIdx.y = dir; 65536 threads/dir =
// 16 waves/CU total. Depth-8 rotating-register prefetch (static indices).
// ---------------------------------------------------------------------------
__global__ __launch_bounds__(256) void irnn_fused(
    const unsigned short* __restrict__ in, unsigned short* __restrict__ outc,
    const float* __restrict__ wu, const float* __restrict__ bu,
    const float* __restrict__ wr, const float* __restrict__ br,
    const float* __restrict__ wd, const float* __restrict__ bd,
    const float* __restrict__ wl, const float* __restrict__ bl)
{
    const int dir = blockIdx.y;
    const float* wv; const float* bv; int pstep, rev;
    if      (dir == 0) { wv = wu; bv = bu; pstep = 64; rev = 1; }  // up
    else if (dir == 1) { wv = wr; bv = br; pstep = 1;  rev = 0; }  // right
    else if (dir == 2) { wv = wd; bv = bd; pstep = 64; rev = 0; }  // down
    else               { wv = wl; bv = bl; pstep = 1;  rev = 1; }  // left
    const int dirOff = dir * 512;

    const int idx = blockIdx.x * 256 + threadIdx.x;  // 0..65535
    const int c = (idx & 255) * 2;                   // channel pair
    const int f = (idx >> 8) & 63;
    const int b = idx >> 14;
    const int fbase = (pstep == 64) ? f : f * 64;

    const float wc0 = wv[c], wc1 = wv[c + 1];
    const float bc0 = bv[c], bc1 = bv[c + 1];
    const int t0 = rev ? 63 : 0;
    const int dp = rev ? -pstep : pstep;
    const int istep = dp * CB / 2;                   // in ushort2 units
    const int ostep = dp * C4 / 2;

    const ushort2* ip = (const ushort2*)(in + ((size_t)b * HW + fbase + (size_t)t0 * pstep) * CB + c);
    ushort2*       op = (ushort2*)(outc + ((size_t)b * HW + fbase + (size_t)t0 * pstep) * C4 + dirOff + c);

    ushort2 x0 = ip[0];
    float s0 = relu_f(bf2f(x0.x));
    float s1 = relu_f(bf2f(x0.y));
    op[0] = make_ushort2(0, 0);

    ushort2 v0 = ip[1*istep], v1 = ip[2*istep], v2 = ip[3*istep], v3 = ip[4*istep],
            v4 = ip[5*istep], v5 = ip[6*istep], v6 = ip[7*istep], v7 = ip[8*istep];

#define DO(kk, vv) {                                                \
    s0 = relu_f(fmaf(s0, wc0, bc0 + bf2f((vv).x)));                 \
    s1 = relu_f(fmaf(s1, wc1, bc1 + bf2f((vv).y)));                 \
    op[(kk)*ostep] = make_ushort2(f2bf(s0), f2bf(s1)); }
    for (int g = 0; g < 6; ++g) {
        const int k0 = 1 + 8 * g;
        DO(k0+0, v0); v0 = ip[(k0+ 8)*istep];
        DO(k0+1, v1); v1 = ip[(k0+ 9)*istep];
        DO(k0+2, v2); v2 = ip[(k0+10)*istep];
        DO(k0+3, v3); v3 = ip[(k0+11)*istep];
        DO(k0+4, v4); v4 = ip[(k0+12)*istep];
        DO(k0+5, v5); v5 = ip[(k0+13)*istep];
        DO(k0+6, v6); v6 = ip[(k0+14)*istep];
        DO(k0+7, v7); v7 = ip[(k0+15)*istep];
    }
    DO(49, v0); v0 = ip[57*istep];
    DO(50, v1); v1 = ip[58*istep];
    DO(51, v2); v2 = ip[59*istep];
    DO(52, v3); v3 = ip[60*istep];
    DO(53, v4); v4 = ip[61*istep];
    DO(54, v5); v5 = ip[62*istep];
    DO(55, v6); v6 = ip[63*istep];
    DO(56, v7);
    DO(57, v0); DO(58, v1); DO(59, v2); DO(60, v3);
    DO(61, v4); DO(62, v5); DO(63, v6);
#undef DO
}

// ---------------------------------------------------------------------------
// ws map: [0,16M) xT | [16M,80M) concat_T | [80M,96M) out0/mid |
//         [96M,..) bf16 weights. conv3x3 "attention" branch is dead -> skipped.
// 6 dispatches: prep | gemm512 | scan1 | gemm2048 | scan2 | gemm2048+relu.
// ---------------------------------------------------------------------------
extern "C" void kernel_launch(void* const* d_in, const int* in_sizes, int n_in,
                              void* d_out, int out_size, void* d_ws, size_t ws_size,
                              hipStream_t stream) {
    const float* x     = (const float*)d_in[0];
    const float* cin_w = (const float*)d_in[7];
    const float* c2_w  = (const float*)d_in[8];
    const float* c3_w  = (const float*)d_in[9];
    const float* i1_wu = (const float*)d_in[10];
    const float* i1_bu = (const float*)d_in[11];
    const float* i1_wr = (const float*)d_in[12];
    const float* i1_br = (const float*)d_in[13];
    const float* i1_wd = (const float*)d_in[14];
    const float* i1_bd = (const float*)d_in[15];
    const float* i1_wl = (const float*)d_in[16];
    const float* i1_bl = (const float*)d_in[17];
    const float* i2_wu = (const float*)d_in[18];
    const float* i2_bu = (const float*)d_in[19];
    const float* i2_wr = (const float*)d_in[20];
    const float* i2_br = (const float*)d_in[21];
    const float* i2_wd = (const float*)d_in[22];
    const float* i2_bd = (const float*)d_in[23];
    const float* i2_wl = (const float*)d_in[24];
    const float* i2_bl = (const float*)d_in[25];

    char* ws = (char*)d_ws;
    unsigned short* xT     = (unsigned short*)(ws);
    unsigned short* concat = (unsigned short*)(ws + (size_t)16 * 1024 * 1024);
    unsigned short* mid    = (unsigned short*)(ws + (size_t)80 * 1024 * 1024);
    unsigned short* wA     = (unsigned short*)(ws + (size_t)96 * 1024 * 1024);
    unsigned short* wB     = (unsigned short*)(wA + 512 * 512);
    unsigned short* wC     = (unsigned short*)(wB + 512 * 2048);

    // 1) prep: x transpose+cast AND weight casts in one launch
    prep_fused<<<4352, 256, 0, stream>>>(x, xT, cin_w, wA, c2_w, wB, c3_w, wC);

    dim3 ggrid(PTOT/128, 4);     // 128 x 4 = 512 blocks = 2/CU
    dim3 sgrid(256, 4);          // channel-pair scan: 65536 threads/dir

    // 2) out0_T = xT @ cin_w^T
    gemm_cl<512, 0><<<ggrid, 256, 0, stream>>>(xT, wA, mid);

    // 3) IRNN #1 -> concat_T
    irnn_fused<<<sgrid, 256, 0, stream>>>(mid, concat,
        i1_wu, i1_bu, i1_wr, i1_br, i1_wd, i1_bd, i1_wl, i1_bl);

    // 4) mid_T = concat_T @ c2_w^T
    gemm_cl<2048, 0><<<ggrid, 256, 0, stream>>>(concat, wB, mid);

    // 5) IRNN #2 -> concat_T
    irnn_fused<<<sgrid, 256, 0, stream>>>(mid, concat,
        i2_wu, i2_bu, i2_wr, i2_br, i2_wd, i2_bd, i2_wl, i2_bl);

    // 6) d_out = relu(concat_T @ c3_w^T), fp32 channel-first
    gemm_cl<2048, 1><<<ggrid, 256, 0, stream>>>(concat, wC, d_out);
}

// Round 17
// 139.105 us; speedup vs baseline: 1.0818x; 1.0125x over previous
//
#include <hip/hip_runtime.h>
#include <stdint.h>

// Geometry (fixed): B=4, C=512, H=W=64
#define NB 4
#define CB 512
#define HH 64
#define WW 64
#define HW 4096
#define C4 2048
#define PTOT (NB*HW)   // 16384 pixels across batch

typedef float  f32x4  __attribute__((ext_vector_type(4)));
typedef short  bf16x8 __attribute__((ext_vector_type(8)));

__device__ __forceinline__ float relu_f(float v){ return v > 0.f ? v : 0.f; }

__device__ __forceinline__ float bf2f(unsigned short u){
    union { uint32_t i; float f; } v; v.i = ((uint32_t)u) << 16; return v.f;
}
__device__ __forceinline__ unsigned short f2bf(float f){
    union { float f; uint32_t i; } v; v.f = f;
    uint32_t r = v.i + 0x7FFFu + ((v.i >> 16) & 1u);   // RNE
    return (unsigned short)(r >> 16);
}

__device__ __forceinline__ void gload16(const void* g, void* l){
    __builtin_amdgcn_global_load_lds(
        (const __attribute__((address_space(1))) uint32_t*)g,
        (__attribute__((address_space(3))) uint32_t*)l, 16, 0, 0);
}

// ---------------------------------------------------------------------------
// Fused prep: blocks [0,2048) transpose+cast x -> xT ; blocks [2048,4352)
// cast the three weight matrices fp32 -> bf16 (one launch instead of two).
// ---------------------------------------------------------------------------
__global__ __launch_bounds__(256) void prep_fused(
    const float* __restrict__ x, unsigned short* __restrict__ xT,
    const float* __restrict__ a, unsigned short* __restrict__ oa,
    const float* __restrict__ b, unsigned short* __restrict__ ob,
    const float* __restrict__ c, unsigned short* __restrict__ oc)
{
    const int t = threadIdx.x;
    if (blockIdx.x >= 2048) {
        int i = (blockIdx.x - 2048) * 256 + t;
        const float* src; unsigned short* dst; int j;
        if (i < 65536)        { src = a; dst = oa; j = i; }
        else if (i < 327680)  { src = b; dst = ob; j = i - 65536; }
        else                  { src = c; dst = oc; j = i - 327680; }
        float4 v = ((const float4*)src)[j];
        ushort4 o;
        o.x = f2bf(v.x); o.y = f2bf(v.y); o.z = f2bf(v.z); o.w = f2bf(v.w);
        ((ushort4*)dst)[j] = o;
        return;
    }
    __shared__ unsigned short tile[64][72];
    const int tb = blockIdx.x;            // 0..2047
    const int p0 = (tb & 63) * 64;
    const int c0 = ((tb >> 6) & 7) * 64;
    const int bb = tb >> 9;

    const int pl = (t & 15) * 4;
    const int cl = t >> 4;
    const float* src = x + ((size_t)bb * CB + c0) * HW + p0;
    #pragma unroll
    for (int r = 0; r < 4; r++) {
        int c2 = cl + r * 16;
        float4 v = *(const float4*)(src + (size_t)c2 * HW + pl);
        tile[pl + 0][c2] = f2bf(v.x);
        tile[pl + 1][c2] = f2bf(v.y);
        tile[pl + 2][c2] = f2bf(v.z);
        tile[pl + 3][c2] = f2bf(v.w);
    }
    __syncthreads();
    unsigned short* dst = xT + ((size_t)bb * HW + p0) * CB + c0;
    const int cl2 = (t & 15) * 4;
    const int pl2 = t >> 4;
    #pragma unroll
    for (int r = 0; r < 4; r++) {
        int p = pl2 + r * 16;
        ushort4 o = *(ushort4*)&tile[p][cl2];
        *(ushort4*)(dst + (size_t)p * CB + cl2) = o;
    }
}

// ---------------------------------------------------------------------------
// Channel-last MFMA GEMM (R13 winner, session best — restored verbatim after
// R16's 2-wave/BK=32 experiment raced and regressed):
//   D[p][o] = sum_k A[p][k] * Bw[o][k]  (bf16, f32 acc)
// Tile 128p x 128o, BK=64, 4 waves, 4x4 16x16x32 frags/wave.
// LDS: 2 x (A 16K | B 16K) = 64K static -> 2 blocks/CU (cross-block overlap
// is the latency hiding; all variants R5-R16 measured equal or worse).
// Loop: STAGE(t+1) ; vmcnt(8) ; barrier ; COMPUTE (hoisted 16 ds_reads,
// no setprio) ; barrier.
// OUTMODE 0: bf16 [PTOT][512] channel-last; 1: fp32 [b][512][HW] + ReLU.
// ---------------------------------------------------------------------------
template<int K, int OUTMODE>
__global__ __launch_bounds__(256) void gemm_cl(
    const unsigned short* __restrict__ A,
    const unsigned short* __restrict__ Bw,
    void* __restrict__ out)
{
    __shared__ __align__(16) char lds[65536];

    const int t    = threadIdx.x;
    const int lane = t & 63;
    const int wid  = t >> 6;
    const int p0   = blockIdx.x * 128;
    const int o0   = blockIdx.y * 128;

    const int l15 = lane & 15;
    const int l4  = lane >> 4;
    const int wp  = (wid & 1) * 64;
    const int wo  = (wid >> 1) * 64;
    const int rowA = wp + l15;
    const int rowB = wo + l15;
    const int swzA = (rowA & 7) << 4;
    const int swzB = (rowB & 7) << 4;

    f32x4 acc[4][4];
    #pragma unroll
    for (int m = 0; m < 4; m++)
        #pragma unroll
        for (int n = 0; n < 4; n++) acc[m][n] = (f32x4)0.f;

    const int srow  = t >> 3;
    const int scolb = (t & 7) * 16;

    auto STAGE = [&](int k0, char* base) {
        #pragma unroll
        for (int q = 0; q < 4; q++) {
            const int row = q * 32 + srow;
            const int kk  = k0 + ((scolb ^ ((row & 7) << 4)) >> 1);
            gload16(A  + (size_t)(p0 + row) * K + kk, base +         q * 4096 + wid * 1024);
            gload16(Bw + (size_t)(o0 + row) * K + kk, base + 16384 + q * 4096 + wid * 1024);
        }
    };
    auto COMPUTE = [&](const char* base) {
        const char* cA = base;
        const char* cB = base + 16384;
        bf16x8 a2[2][4], b2[2][4];
        #pragma unroll
        for (int kh = 0; kh < 2; kh++) {
            const int colb = kh * 64 + l4 * 16;
            #pragma unroll
            for (int m = 0; m < 4; m++)
                a2[kh][m] = *(const bf16x8*)(cA + (rowA + m * 16) * 128 + (colb ^ swzA));
            #pragma unroll
            for (int n = 0; n < 4; n++)
                b2[kh][n] = *(const bf16x8*)(cB + (rowB + n * 16) * 128 + (colb ^ swzB));
        }
        #pragma unroll
        for (int kh = 0; kh < 2; kh++)
            #pragma unroll
            for (int m = 0; m < 4; m++)
                #pragma unroll
                for (int n = 0; n < 4; n++)
                    acc[m][n] = __builtin_amdgcn_mfma_f32_16x16x32_bf16(
                                    a2[kh][m], b2[kh][n], acc[m][n], 0, 0, 0);
    };

    const int NT = K / 64;
    STAGE(0, lds);                                  // 8 loads in flight
    #pragma unroll 2
    for (int tt = 0; tt < NT - 1; ++tt) {
        char* cbase = lds + ((tt & 1) ? 32768 : 0);
        char* nbase = lds + ((tt & 1) ? 0 : 32768);
        STAGE((tt + 1) * 64, nbase);                // +8 loads (tile t+1)
        asm volatile("s_waitcnt vmcnt(8)" ::: "memory");  // drain ONLY tile t's 8
        __builtin_amdgcn_s_barrier();               // tile t resident everywhere
        __builtin_amdgcn_sched_barrier(0);
        COMPUTE(cbase);                             // MFMA current (prefetch in flight)
        __builtin_amdgcn_s_barrier();               // all reads of cbase done
    }
    asm volatile("s_waitcnt vmcnt(0)" ::: "memory");
    __builtin_amdgcn_s_barrier();
    __builtin_amdgcn_sched_barrier(0);
    COMPUTE(lds + (((NT - 1) & 1) ? 32768 : 0));

    if (OUTMODE == 0) {
        unsigned short* op = (unsigned short*)out;
        #pragma unroll
        for (int m = 0; m < 4; m++)
            #pragma unroll
            for (int r = 0; r < 4; r++) {
                const int p = p0 + wp + m * 16 + l4 * 4 + r;
                #pragma unroll
                for (int n = 0; n < 4; n++) {
                    const int o = wo + n * 16 + l15 + o0;
                    op[(size_t)p * CB + o] = f2bf(acc[m][n][r]);
                }
            }
    } else {
        __syncthreads();                   // protect LDS reuse vs last COMPUTE reads
        float (*tl)[132] = (float(*)[132])lds;
        const int bb   = p0 >> 12;
        const int phw0 = p0 & (HW - 1);
        #pragma unroll
        for (int half = 0; half < 2; half++) {
            if ((wid >> 1) == half) {
                #pragma unroll
                for (int n = 0; n < 4; n++)
                    #pragma unroll
                    for (int m = 0; m < 4; m++)
                        #pragma unroll
                        for (int r = 0; r < 4; r++)
                            tl[n * 16 + l15][wp + m * 16 + l4 * 4 + r] = acc[m][n][r];
            }
            __syncthreads();
            const int orow = t >> 2;
            const int pseg = (t & 3) * 32;
            float* dst = (float*)out +
                ((size_t)(bb * CB + o0 + half * 64 + orow)) * HW + phw0 + pseg;
            #pragma unroll
            for (int j = 0; j < 8; j++) {
                float4 v = *(float4*)&tl[orow][pseg + j * 4];
                v.x = relu_f(v.x); v.y = relu_f(v.y); v.z = relu_f(v.z); v.w = relu_f(v.w);
                *(float4*)(dst + j * 4) = v;
            }
            __syncthreads();
        }
    }
}

// ---------------------------------------------------------------------------
// Fused 4-direction IRNN scan, channel-last, scalar channel per thread.
// grid (512, 4): blockIdx.y = dir (0=u,1=r,2=d,3=l). Depth-8 reg prefetch.
// ---------------------------------------------------------------------------
__global__ __launch_bounds__(256) void irnn_fused(
    const unsigned short* __restrict__ in, unsigned short* __restrict__ outc,
    const float* __restrict__ wu, const float* __restrict__ bu,
    const float* __restrict__ wr, const float* __restrict__ br,
    const float* __restrict__ wd, const float* __restrict__ bd,
    const float* __restrict__ wl, const float* __restrict__ bl)
{
    const int dir = blockIdx.y;
    const float* wv; const float* bv; int pstep, rev;
    if      (dir == 0) { wv = wu; bv = bu; pstep = 64; rev = 1; }  // up
    else if (dir == 1) { wv = wr; bv = br; pstep = 1;  rev = 0; }  // right
    else if (dir == 2) { wv = wd; bv = bd; pstep = 64; rev = 0; }  // down
    else               { wv = wl; bv = bl; pstep = 1;  rev = 1; }  // left
    const int dirOff = dir * 512;

    const int idx = blockIdx.x * 256 + threadIdx.x;  // 0..131071
    const int c = idx & 511;
    const int f = (idx >> 9) & 63;
    const int b = idx >> 15;
    const int fbase = (pstep == 64) ? f : f * 64;

    const float wc = wv[c], bc = bv[c];
    const int t0 = rev ? 63 : 0;
    const int dp = rev ? -pstep : pstep;
    const int istep = dp * CB;
    const int ostep = dp * C4;

    const unsigned short* ip = in   + ((size_t)b * HW + fbase + (size_t)t0 * pstep) * CB + c;
    unsigned short*       op = outc + ((size_t)b * HW + fbase + (size_t)t0 * pstep) * C4 + dirOff + c;

    float s = relu_f(bf2f(ip[0]));
    op[0] = 0;

    unsigned short v0 = ip[1*istep], v1 = ip[2*istep], v2 = ip[3*istep], v3 = ip[4*istep],
                   v4 = ip[5*istep], v5 = ip[6*istep], v6 = ip[7*istep], v7 = ip[8*istep];

#define DO(kk, vv) { s = relu_f(fmaf(s, wc, bc + bf2f(vv))); op[(kk)*ostep] = f2bf(s); }
    for (int g = 0; g < 6; ++g) {
        const int k0 = 1 + 8 * g;
        DO(k0+0, v0); v0 = ip[(k0+ 8)*istep];
        DO(k0+1, v1); v1 = ip[(k0+ 9)*istep];
        DO(k0+2, v2); v2 = ip[(k0+10)*istep];
        DO(k0+3, v3); v3 = ip[(k0+11)*istep];
        DO(k0+4, v4); v4 = ip[(k0+12)*istep];
        DO(k0+5, v5); v5 = ip[(k0+13)*istep];
        DO(k0+6, v6); v6 = ip[(k0+14)*istep];
        DO(k0+7, v7); v7 = ip[(k0+15)*istep];
    }
    DO(49, v0); v0 = ip[57*istep];
    DO(50, v1); v1 = ip[58*istep];
    DO(51, v2); v2 = ip[59*istep];
    DO(52, v3); v3 = ip[60*istep];
    DO(53, v4); v4 = ip[61*istep];
    DO(54, v5); v5 = ip[62*istep];
    DO(55, v6); v6 = ip[63*istep];
    DO(56, v7);
    DO(57, v0); DO(58, v1); DO(59, v2); DO(60, v3);
    DO(61, v4); DO(62, v5); DO(63, v6);
#undef DO
}

// ---------------------------------------------------------------------------
// ws map: [0,16M) xT | [16M,80M) concat_T | [80M,96M) out0/mid |
//         [96M,..) bf16 weights. conv3x3 "attention" branch is dead -> skipped.
// 6 dispatches: prep | gemm512 | scan1 | gemm2048 | scan2 | gemm2048+relu.
// ---------------------------------------------------------------------------
extern "C" void kernel_launch(void* const* d_in, const int* in_sizes, int n_in,
                              void* d_out, int out_size, void* d_ws, size_t ws_size,
                              hipStream_t stream) {
    const float* x     = (const float*)d_in[0];
    const float* cin_w = (const float*)d_in[7];
    const float* c2_w  = (const float*)d_in[8];
    const float* c3_w  = (const float*)d_in[9];
    const float* i1_wu = (const float*)d_in[10];
    const float* i1_bu = (const float*)d_in[11];
    const float* i1_wr = (const float*)d_in[12];
    const float* i1_br = (const float*)d_in[13];
    const float* i1_wd = (const float*)d_in[14];
    const float* i1_bd = (const float*)d_in[15];
    const float* i1_wl = (const float*)d_in[16];
    const float* i1_bl = (const float*)d_in[17];
    const float* i2_wu = (const float*)d_in[18];
    const float* i2_bu = (const float*)d_in[19];
    const float* i2_wr = (const float*)d_in[20];
    const float* i2_br = (const float*)d_in[21];
    const float* i2_wd = (const float*)d_in[22];
    const float* i2_bd = (const float*)d_in[23];
    const float* i2_wl = (const float*)d_in[24];
    const float* i2_bl = (const float*)d_in[25];

    char* ws = (char*)d_ws;
    unsigned short* xT     = (unsigned short*)(ws);
    unsigned short* concat = (unsigned short*)(ws + (size_t)16 * 1024 * 1024);
    unsigned short* mid    = (unsigned short*)(ws + (size_t)80 * 1024 * 1024);
    unsigned short* wA     = (unsigned short*)(ws + (size_t)96 * 1024 * 1024);
    unsigned short* wB     = (unsigned short*)(wA + 512 * 512);
    unsigned short* wC     = (unsigned short*)(wB + 512 * 2048);

    // 1) prep: x transpose+cast AND weight casts in one launch
    prep_fused<<<4352, 256, 0, stream>>>(x, xT, cin_w, wA, c2_w, wB, c3_w, wC);

    dim3 ggrid(PTOT/128, 4);     // 128 x 4 = 512 blocks = 2/CU
    dim3 sgrid(512, 4);

    // 2) out0_T = xT @ cin_w^T
    gemm_cl<512, 0><<<ggrid, 256, 0, stream>>>(xT, wA, mid);

    // 3) IRNN #1 -> concat_T
    irnn_fused<<<sgrid, 256, 0, stream>>>(mid, concat,
        i1_wu, i1_bu, i1_wr, i1_br, i1_wd, i1_bd, i1_wl, i1_bl);

    // 4) mid_T = concat_T @ c2_w^T
    gemm_cl<2048, 0><<<ggrid, 256, 0, stream>>>(concat, wB, mid);

    // 5) IRNN #2 -> concat_T
    irnn_fused<<<sgrid, 256, 0, stream>>>(mid, concat,
        i2_wu, i2_bu, i2_wr, i2_br, i2_wd, i2_bd, i2_wl, i2_bl);

    // 6) d_out = relu(concat_T @ c3_w^T), fp32 channel-first
    gemm_cl<2048, 1><<<ggrid, 256, 0, stream>>>(concat, wC, d_out);
}